// Round 5
// baseline (90.632 us; speedup 1.0000x reference)
//
#include <hip/hip_runtime.h>
#include <math.h>

#define BHn 16
#define SLEN 4096
#define Dd 64
#define Cc 64
#define NCC 64
#define EPSF 1e-6f
#define PD 65

// ---------------------------------------------------------------------------
// kA: per (head, chunk) UT transform.  (round-4 form, measured == round-0:
// two parallel solve waves (wave0 = W, wave2 = U), 52 VGPR, 4 blocks/CU)
// ---------------------------------------------------------------------------
__global__ __launch_bounds__(256, 4) void kA(
    const float* __restrict__ kg, const float* __restrict__ vg,
    const float* __restrict__ betag, float* __restrict__ WTg, float* __restrict__ UTg,
    float* __restrict__ wlast, float* __restrict__ ulast)
{
    const int n = blockIdx.x, bh = blockIdx.y, tid = threadIdx.x;
    __shared__ float KT[64 * PD];   // kn^T, then (g*v)^T
    __shared__ float SM[64 * PD];
    __shared__ float gl[64];

    const size_t base = ((size_t)bh * SLEN + (size_t)n * Cc) * Dd;

    if (tid < 64) {
        const float b = betag[(size_t)bh * SLEN + n * Cc + tid];
        gl[tid] = fminf(fmaxf(b, EPSF), 1.0f - EPSF);
    }
#pragma unroll
    for (int p = 0; p < 4; p++) {
        const int flat = p * 1024 + tid * 4;
        const int row = flat >> 6, d0 = flat & 63;
        const float4 a = *(const float4*)(kg + base + flat);
        float ss = a.x * a.x + a.y * a.y + a.z * a.z + a.w * a.w;
        ss += __shfl_xor(ss, 1); ss += __shfl_xor(ss, 2);
        ss += __shfl_xor(ss, 4); ss += __shfl_xor(ss, 8);
        const float inv = 1.0f / (sqrtf(ss) + EPSF);
        KT[(d0 + 0) * PD + row] = a.x * inv;
        KT[(d0 + 1) * PD + row] = a.y * inv;
        KT[(d0 + 2) * PD + row] = a.z * inv;
        KT[(d0 + 3) * PD + row] = a.w * inv;
    }
    __syncthreads();

    float sol[64];
    if (tid < 64) {
#pragma unroll
        for (int j4 = 0; j4 < 16; j4++) {
            const float4 t4 = *(const float4*)&KT[tid * PD + j4 * 4];
            sol[j4 * 4 + 0] = t4.x * gl[j4 * 4 + 0];
            sol[j4 * 4 + 1] = t4.y * gl[j4 * 4 + 1];
            sol[j4 * 4 + 2] = t4.z * gl[j4 * 4 + 2];
            sol[j4 * 4 + 3] = t4.w * gl[j4 * 4 + 3];
        }
    } else if (tid < 200) {
        const int t = tid - 64;
        int ti = (int)((sqrtf(8.0f * (float)t + 1.0f) - 1.0f) * 0.5f);
        while (ti * (ti + 1) / 2 > t) --ti;
        while ((ti + 1) * (ti + 2) / 2 <= t) ++ti;
        const int tj = t - ti * (ti + 1) / 2;
        const int i0 = ti * 4, j0 = tj * 4;
        float sa[4][4];
#pragma unroll
        for (int r = 0; r < 4; r++)
#pragma unroll
            for (int c2 = 0; c2 < 4; c2++) sa[r][c2] = 0.f;
        for (int d = 0; d < 64; d++) {
            const float4 a = *(const float4*)&KT[d * PD + i0];
            const float4 b = *(const float4*)&KT[d * PD + j0];
            const float av[4] = {a.x, a.y, a.z, a.w};
            const float bv[4] = {b.x, b.y, b.z, b.w};
#pragma unroll
            for (int r = 0; r < 4; r++)
#pragma unroll
                for (int c2 = 0; c2 < 4; c2++) sa[r][c2] += av[r] * bv[c2];
        }
#pragma unroll
        for (int r = 0; r < 4; r++) {
            const float gg = gl[i0 + r];
            *(float4*)&SM[(i0 + r) * PD + j0] =
                make_float4(sa[r][0] * gg, sa[r][1] * gg, sa[r][2] * gg, sa[r][3] * gg);
        }
    }
    __syncthreads();

#pragma unroll
    for (int p = 0; p < 4; p++) {
        const int flat = p * 1024 + tid * 4;
        const int row = flat >> 6, d0 = flat & 63;
        const float4 a = *(const float4*)(vg + base + flat);
        const float gg = gl[row];
        KT[(d0 + 0) * PD + row] = a.x * gg;
        KT[(d0 + 1) * PD + row] = a.y * gg;
        KT[(d0 + 2) * PD + row] = a.z * gg;
        KT[(d0 + 3) * PD + row] = a.w * gg;
    }
    __syncthreads();

    if (tid >= 128 && tid < 192) {
        const int c = tid - 128;
#pragma unroll
        for (int j4 = 0; j4 < 16; j4++) {
            const float4 t4 = *(const float4*)&KT[c * PD + j4 * 4];
            sol[j4 * 4 + 0] = t4.x; sol[j4 * 4 + 1] = t4.y;
            sol[j4 * 4 + 2] = t4.z; sol[j4 * 4 + 3] = t4.w;
        }
    }
    if (tid < 64 || (tid >= 128 && tid < 192)) {
        const int c = tid & 63;
#pragma unroll
        for (int b = 0; b < 8; b++) {
            const int i0 = b * 8;
            float acc[8];
#pragma unroll
            for (int r = 0; r < 8; r++) acc[r] = sol[i0 + r];
#pragma unroll
            for (int j4 = 0; j4 < 2 * b; j4++) {
                const int j = j4 * 4;
                const float s0 = sol[j + 0], s1 = sol[j + 1];
                const float s2 = sol[j + 2], s3 = sol[j + 3];
#pragma unroll
                for (int r = 0; r < 8; r++) {
                    const float4 m4 = *(const float4*)&SM[(i0 + r) * PD + j];
                    acc[r] -= m4.x * s0 + m4.y * s1 + m4.z * s2 + m4.w * s3;
                }
            }
#pragma unroll
            for (int il = 1; il < 8; il++)
#pragma unroll
                for (int jl = 0; jl < il; jl++)
                    acc[il] -= SM[(i0 + il) * PD + i0 + jl] * acc[jl];
#pragma unroll
            for (int r = 0; r < 8; r++) sol[i0 + r] = acc[r];
        }
        float* dst = (tid < 64 ? WTg : UTg) +
                     (size_t)(bh * NCC + n) * Cc * Dd + (size_t)c * 64;
#pragma unroll
        for (int j4 = 0; j4 < 16; j4++)
            *(float4*)(dst + j4 * 4) = make_float4(sol[j4 * 4 + 0], sol[j4 * 4 + 1],
                                                   sol[j4 * 4 + 2], sol[j4 * 4 + 3]);
        float* lst = (tid < 64 ? wlast : ulast);
        lst[(size_t)(bh * NCC + n) * 64 + c] = sol[63];
    }
}

// ---------------------------------------------------------------------------
// kB: chunk-level delta rule (16 blocks). Register solve.  (unchanged)
// ---------------------------------------------------------------------------
__global__ __launch_bounds__(256) void kB(
    const float* __restrict__ wlast, const float* __restrict__ ulast,
    float* __restrict__ Uvg)
{
    const int bh = blockIdx.x, tid = threadIdx.x;
    __shared__ float WL[64 * PD];
    __shared__ float UL[64 * PD];
    __shared__ float SM[64 * PD];
    const size_t gbase = (size_t)bh * NCC * 64;

#pragma unroll
    for (int p = 0; p < 4; p++) {
        const int flat = p * 1024 + tid * 4;
        const int m = flat >> 6, d = flat & 63;
        *(float4*)&WL[m * PD + d] = *(const float4*)(wlast + gbase + flat);
        *(float4*)&UL[m * PD + d] = *(const float4*)(ulast + gbase + flat);
    }
    __syncthreads();

    if (tid < 136) {
        int ti = (int)((sqrtf(8.0f * (float)tid + 1.0f) - 1.0f) * 0.5f);
        while (ti * (ti + 1) / 2 > tid) --ti;
        while ((ti + 1) * (ti + 2) / 2 <= tid) ++ti;
        const int tj = tid - ti * (ti + 1) / 2;
        const int i0 = ti * 4, j0 = tj * 4;
        float sa[4][4];
#pragma unroll
        for (int r = 0; r < 4; r++)
#pragma unroll
            for (int c2 = 0; c2 < 4; c2++) sa[r][c2] = 0.f;
        for (int d4 = 0; d4 < 16; d4++) {
            const int d = d4 * 4;
            float4 ar[4], bc[4];
#pragma unroll
            for (int r = 0; r < 4; r++) ar[r] = *(const float4*)&WL[(i0 + r) * PD + d];
#pragma unroll
            for (int c2 = 0; c2 < 4; c2++) bc[c2] = *(const float4*)&WL[(j0 + c2) * PD + d];
#pragma unroll
            for (int r = 0; r < 4; r++)
#pragma unroll
                for (int c2 = 0; c2 < 4; c2++)
                    sa[r][c2] += ar[r].x * bc[c2].x + ar[r].y * bc[c2].y +
                                 ar[r].z * bc[c2].z + ar[r].w * bc[c2].w;
        }
#pragma unroll
        for (int r = 0; r < 4; r++)
            *(float4*)&SM[(i0 + r) * PD + j0] =
                make_float4(sa[r][0], sa[r][1], sa[r][2], sa[r][3]);
    }
    __syncthreads();

    if (tid < 64) {
        const int e = tid;
        float sol[64];
#pragma unroll
        for (int m = 0; m < 64; m++) sol[m] = UL[m * PD + e];
#pragma unroll
        for (int b = 0; b < 8; b++) {
            const int i0 = b * 8;
            float acc[8];
#pragma unroll
            for (int r = 0; r < 8; r++) acc[r] = sol[i0 + r];
#pragma unroll
            for (int j4 = 0; j4 < 2 * b; j4++) {
                const int j = j4 * 4;
                const float s0 = sol[j + 0], s1 = sol[j + 1];
                const float s2 = sol[j + 2], s3 = sol[j + 3];
#pragma unroll
                for (int r = 0; r < 8; r++) {
                    const float4 m4 = *(const float4*)&SM[(i0 + r) * PD + j];
                    acc[r] -= m4.x * s0 + m4.y * s1 + m4.z * s2 + m4.w * s3;
                }
            }
#pragma unroll
            for (int il = 1; il < 8; il++)
#pragma unroll
                for (int jl = 0; jl < il; jl++)
                    acc[il] -= SM[(i0 + il) * PD + i0 + jl] * acc[jl];
#pragma unroll
            for (int r = 0; r < 8; r++) sol[i0 + r] = acc[r];
        }
#pragma unroll
        for (int m = 0; m < 64; m++) Uvg[gbase + (size_t)m * 64 + e] = sol[m];
    }
}

// ---------------------------------------------------------------------------
// kC round-5: e-split for wave residency.  1024 blocks (was 512): block
// (bx, bh) handles e-half h = bx&1 of the balanced chunk pair (63-px, px),
// px = bx>>1.  Round-0 had 2 blocks/CU = 2 waves/SIMD -- latency-starved
// (all utilizations low).  Now 4 blocks/CU (grid-exact), 16 waves/CU.
// LDS trimmed to EXACTLY 40960 B: X1 unpadded 16K + X2s (qn^T, XOR-swizzled
// cols instead of pad-65) 16K + HBU 8K (stages the Uval e-half, then holds
// h[d][e-half]).  qn^T is built once at stage time (no rebuild pass).
// All 256 threads active in every phase (rounds 1/2 lesson).
// Per-thread tile 4t x 2e; math per output element identical to round-0.
// ---------------------------------------------------------------------------
__global__ __launch_bounds__(256, 4) void kC(
    const float* __restrict__ qg, const float* __restrict__ WTg,
    const float* __restrict__ UTg, const float* __restrict__ wlast,
    const float* __restrict__ Uvg, float* __restrict__ outg)
{
    const int bx = blockIdx.x, bh = blockIdx.y, tid = threadIdx.x;
    const int px = bx >> 1, h = bx & 1;
    __shared__ float X1[4096];    // wlast[m][d] -> W^T[d][t]
    __shared__ float X2s[4096];   // qn^T[d][t], col ^= ((d>>3)&7)<<2
    __shared__ float HBU[2048];   // Uval[m][e'] -> h[d][e']   (e' = e - 32h)
    const size_t lbase = (size_t)bh * NCC * 64;
    const int t0 = (tid >> 4) * 4, e0 = (tid & 15) * 2;

    for (int pass = 0; pass < 2; ++pass) {
        const int n = pass ? px : 63 - px;
        const size_t qbase = ((size_t)bh * SLEN + (size_t)n * Cc) * Dd;
        const size_t wbase = (size_t)(bh * NCC + n) * Cc * Dd;
        if (pass) __syncthreads();   // protect LDS reuse across passes

        float4 wt[4];
        // stage: X1 <- wlast, X2s <- qn^T (swizzled transposed writes),
        //        HBU <- Uval e-half, wt <- W^T rows (regs, used after ph1)
#pragma unroll
        for (int p = 0; p < 4; p++) {
            const int flat = p * 1024 + tid * 4;
            const int row = flat >> 6, d0 = flat & 63;   // token row, dims d0..d0+3
            *(float4*)&X1[row * 64 + d0] = *(const float4*)(wlast + lbase + flat);
            wt[p] = *(const float4*)(WTg + wbase + flat);
            const float4 qa = *(const float4*)(qg + qbase + flat);
            float ss = qa.x * qa.x + qa.y * qa.y + qa.z * qa.z + qa.w * qa.w;
            ss += __shfl_xor(ss, 1); ss += __shfl_xor(ss, 2);
            ss += __shfl_xor(ss, 4); ss += __shfl_xor(ss, 8);
            const float qinv = 1.0f / (sqrtf(ss) + EPSF);
            const int cs = row ^ (((d0 >> 3) & 7) << 2);  // d0 4-aligned: same swz for d0..d0+3
            X2s[(d0 + 0) * 64 + cs] = qa.x * qinv;
            X2s[(d0 + 1) * 64 + cs] = qa.y * qinv;
            X2s[(d0 + 2) * 64 + cs] = qa.z * qinv;
            X2s[(d0 + 3) * 64 + cs] = qa.w * qinv;
        }
#pragma unroll
        for (int p2 = 0; p2 < 2; p2++) {
            const int flat = p2 * 1024 + tid * 4;        // 2048 elems: [64 m][32 e']
            const int m = flat >> 5, e = flat & 31;
            *(float4*)&HBU[m * 32 + e] =
                *(const float4*)(Uvg + lbase + (size_t)m * 64 + h * 32 + e);
        }
        __syncthreads();

        // ph1: h[d][e'] tile accumulation over earlier chunks (4d x 2e per thread)
        float ha[4][2];
#pragma unroll
        for (int r = 0; r < 4; r++) { ha[r][0] = 0.f; ha[r][1] = 0.f; }
        for (int m = 0; m < n; m++) {
            const float4 a = *(const float4*)&X1[m * 64 + t0];
            const float2 b = *(const float2*)&HBU[m * 32 + e0];
            ha[0][0] += a.x * b.x; ha[0][1] += a.x * b.y;
            ha[1][0] += a.y * b.x; ha[1][1] += a.y * b.y;
            ha[2][0] += a.z * b.x; ha[2][1] += a.z * b.y;
            ha[3][0] += a.w * b.x; ha[3][1] += a.w * b.y;
        }
        __syncthreads();   // Uval reads + X1 (wlast) reads done

        // HBU <- h; X1 <- W^T (flat from regs)
#pragma unroll
        for (int r = 0; r < 4; r++) {
            float2 hw; hw.x = ha[r][0]; hw.y = ha[r][1];
            *(float2*)&HBU[(t0 + r) * 32 + e0] = hw;
        }
#pragma unroll
        for (int p = 0; p < 4; p++) {
            const int flat = p * 1024 + tid * 4;
            const int d = flat >> 6, t = flat & 63;
            *(float4*)&X1[d * 64 + t] = wt[p];
        }
        __syncthreads();

        // ph3: kth = W h, oin = qn h  (4t x 2e per thread)
        float kth[4][2], oin[4][2];
#pragma unroll
        for (int r = 0; r < 4; r++) {
            kth[r][0] = 0.f; kth[r][1] = 0.f;
            oin[r][0] = 0.f; oin[r][1] = 0.f;
        }
#pragma unroll 4
        for (int d = 0; d < 64; d++) {
            const int sw = ((d >> 3) & 7) << 2;
            const float4 wv = *(const float4*)&X1[d * 64 + t0];
            const float4 qv = *(const float4*)&X2s[d * 64 + (t0 ^ sw)];
            const float2 hv = *(const float2*)&HBU[d * 32 + e0];
            kth[0][0] += wv.x * hv.x; kth[0][1] += wv.x * hv.y;
            kth[1][0] += wv.y * hv.x; kth[1][1] += wv.y * hv.y;
            kth[2][0] += wv.z * hv.x; kth[2][1] += wv.z * hv.y;
            kth[3][0] += wv.w * hv.x; kth[3][1] += wv.w * hv.y;
            oin[0][0] += qv.x * hv.x; oin[0][1] += qv.x * hv.y;
            oin[1][0] += qv.y * hv.x; oin[1][1] += qv.y * hv.y;
            oin[2][0] += qv.z * hv.x; oin[2][1] += qv.z * hv.y;
            oin[3][0] += qv.w * hv.x; oin[3][1] += qv.w * hv.y;
        }

        // epilogue: U^T tile from global (L2-hot), qn from X2s; out = qn.*(U-kth)+oin
        float* oc = outg + qbase;
        float o4[4][2];
#pragma unroll
        for (int s = 0; s < 2; s++) {
            const int e = h * 32 + e0 + s;
            const int swe = ((e >> 3) & 7) << 2;
            const float4 u4 = *(const float4*)(UTg + wbase + (size_t)e * 64 + t0);
            const float4 q4 = *(const float4*)&X2s[e * 64 + (t0 ^ swe)];
            o4[0][s] = q4.x * (u4.x - kth[0][s]) + oin[0][s];
            o4[1][s] = q4.y * (u4.y - kth[1][s]) + oin[1][s];
            o4[2][s] = q4.z * (u4.z - kth[2][s]) + oin[2][s];
            o4[3][s] = q4.w * (u4.w - kth[3][s]) + oin[3][s];
        }
#pragma unroll
        for (int r = 0; r < 4; r++) {
            float2 ow; ow.x = o4[r][0]; ow.y = o4[r][1];
            *(float2*)(oc + (size_t)(t0 + r) * 64 + h * 32 + e0) = ow;
        }
    }
}

extern "C" void kernel_launch(void* const* d_in, const int* in_sizes, int n_in,
                              void* d_out, int out_size, void* d_ws, size_t ws_size,
                              hipStream_t stream) {
    const float* q    = (const float*)d_in[0];
    const float* k    = (const float*)d_in[1];
    const float* v    = (const float*)d_in[2];
    const float* beta = (const float*)d_in[3];
    float* out = (float*)d_out;

    float* WTg   = (float*)d_ws;                              // [BH][NC][64][64] (W^T)
    float* UTg   = WTg + (size_t)BHn * NCC * Cc * Dd;         // [BH][NC][64][64] (U^T)
    float* wlast = UTg + (size_t)BHn * NCC * Cc * Dd;         // [BH][NC][64]
    float* ulast = wlast + (size_t)BHn * NCC * 64;            // [BH][NC][64]
    float* Uvg   = ulast + (size_t)BHn * NCC * 64;            // [BH][NC][64]

    kA<<<dim3(NCC, BHn), 256, 0, stream>>>(k, v, beta, WTg, UTg, wlast, ulast);
    kB<<<dim3(BHn), 256, 0, stream>>>(wlast, ulast, Uvg);
    kC<<<dim3(64, BHn), 256, 0, stream>>>(q, WTg, UTg, wlast, Uvg, out);
}

// Round 6
// 86.493 us; speedup vs baseline: 1.0478x; 1.0478x over previous
//
#include <hip/hip_runtime.h>
#include <math.h>

#define BHn 16
#define SLEN 4096
#define Dd 64
#define Cc 64
#define NCC 64
#define EPSF 1e-6f
#define PD 65

// ---------------------------------------------------------------------------
// kA round-6: solve SM traffic moved off the LDS pipe.
//   * S-phase stores the strict-lower triangle FLATTENED: e = i(i-1)/2 + j,
//     addr = e + (e>>5)  (pad 1/32 => b128 loads land 2 lanes/bank = free).
//   * Each solve lane loads its 32 contiguous elements (8 x b128, ONE pass
//     over SM per wave instead of 672 broadcast reads), negates them.
//   * Elimination = 2016 fully-unrolled {v_readlane; v_fmac} pairs: SM values
//     broadcast through VALU (per-SIMD) instead of the CU-shared LDS return
//     path (~53K cycles/CU in round-0, the dominant kA term).
//   * j-outer order: consecutive FMAs hit different sol[i] (no dep chains),
//     identical per-element update order to round-0.
// Two parallel solve waves kept (wave0 = W, wave2 = U), 4 blocks/CU.
// ---------------------------------------------------------------------------
__global__ __launch_bounds__(256, 4) void kA(
    const float* __restrict__ kg, const float* __restrict__ vg,
    const float* __restrict__ betag, float* __restrict__ WTg, float* __restrict__ UTg,
    float* __restrict__ wlast, float* __restrict__ ulast)
{
    const int n = blockIdx.x, bh = blockIdx.y, tid = threadIdx.x;
    __shared__ float KT[64 * PD];   // kn^T, then (g*v)^T
    __shared__ float SMf[2112];     // flattened strict-lower SM, addr = e + (e>>5)
    __shared__ float gl[64];

    const size_t base = ((size_t)bh * SLEN + (size_t)n * Cc) * Dd;

    if (tid < 64) {
        const float b = betag[(size_t)bh * SLEN + n * Cc + tid];
        gl[tid] = fminf(fmaxf(b, EPSF), 1.0f - EPSF);
    }
    // build KT = kn^T : coalesced float4 row loads, 16-lane norm, transposed
    // scalar writes (bank = (d+t)%32, exactly 2 lanes/bank => free)
#pragma unroll
    for (int p = 0; p < 4; p++) {
        const int flat = p * 1024 + tid * 4;
        const int row = flat >> 6, d0 = flat & 63;
        const float4 a = *(const float4*)(kg + base + flat);
        float ss = a.x * a.x + a.y * a.y + a.z * a.z + a.w * a.w;
        ss += __shfl_xor(ss, 1); ss += __shfl_xor(ss, 2);
        ss += __shfl_xor(ss, 4); ss += __shfl_xor(ss, 8);
        const float inv = 1.0f / (sqrtf(ss) + EPSF);
        KT[(d0 + 0) * PD + row] = a.x * inv;
        KT[(d0 + 1) * PD + row] = a.y * inv;
        KT[(d0 + 2) * PD + row] = a.z * inv;
        KT[(d0 + 3) * PD + row] = a.w * inv;
    }
    __syncthreads();

    float sol[64];
    if (tid < 64) {
        // wave0: load W solve column = KT[tid][:] * g[:]  (concurrent with S)
#pragma unroll
        for (int j4 = 0; j4 < 16; j4++) {
            const float4 t4 = *(const float4*)&KT[tid * PD + j4 * 4];
            sol[j4 * 4 + 0] = t4.x * gl[j4 * 4 + 0];
            sol[j4 * 4 + 1] = t4.y * gl[j4 * 4 + 1];
            sol[j4 * 4 + 2] = t4.z * gl[j4 * 4 + 2];
            sol[j4 * 4 + 3] = t4.w * gl[j4 * 4 + 3];
        }
    } else if (tid < 200) {
        // threads 64..199: S lower 4x4 tiles from KT; rows scaled by g_i;
        // stores go to the FLATTENED triangle (diag tiles: strict-lower only)
        const int t = tid - 64;
        int ti = (int)((sqrtf(8.0f * (float)t + 1.0f) - 1.0f) * 0.5f);
        while (ti * (ti + 1) / 2 > t) --ti;
        while ((ti + 1) * (ti + 2) / 2 <= t) ++ti;
        const int tj = t - ti * (ti + 1) / 2;
        const int i0 = ti * 4, j0 = tj * 4;
        float sa[4][4];
#pragma unroll
        for (int r = 0; r < 4; r++)
#pragma unroll
            for (int c2 = 0; c2 < 4; c2++) sa[r][c2] = 0.f;
        for (int d = 0; d < 64; d++) {
            const float4 a = *(const float4*)&KT[d * PD + i0];
            const float4 b = *(const float4*)&KT[d * PD + j0];
            const float av[4] = {a.x, a.y, a.z, a.w};
            const float bv[4] = {b.x, b.y, b.z, b.w};
#pragma unroll
            for (int r = 0; r < 4; r++)
#pragma unroll
                for (int c2 = 0; c2 < 4; c2++) sa[r][c2] += av[r] * bv[c2];
        }
#pragma unroll
        for (int r = 0; r < 4; r++) {
            const int i = i0 + r;
            const int eb = (i * (i - 1)) / 2 + j0;
            const float gg = gl[i];
#pragma unroll
            for (int c2 = 0; c2 < 4; c2++) {
                if (ti != tj || c2 < r) {
                    const int e = eb + c2;
                    SMf[e + (e >> 5)] = sa[r][c2] * gg;
                }
            }
        }
    }
    __syncthreads();

    // overwrite KT with (g*v)^T
#pragma unroll
    for (int p = 0; p < 4; p++) {
        const int flat = p * 1024 + tid * 4;
        const int row = flat >> 6, d0 = flat & 63;
        const float4 a = *(const float4*)(vg + base + flat);
        const float gg = gl[row];
        KT[(d0 + 0) * PD + row] = a.x * gg;
        KT[(d0 + 1) * PD + row] = a.y * gg;
        KT[(d0 + 2) * PD + row] = a.z * gg;
        KT[(d0 + 3) * PD + row] = a.w * gg;
    }
    __syncthreads();

    if (tid >= 128 && tid < 192) {
        // wave2: load U solve column = (g*v)^T row
        const int c = tid - 128;
#pragma unroll
        for (int j4 = 0; j4 < 16; j4++) {
            const float4 t4 = *(const float4*)&KT[c * PD + j4 * 4];
            sol[j4 * 4 + 0] = t4.x; sol[j4 * 4 + 1] = t4.y;
            sol[j4 * 4 + 2] = t4.z; sol[j4 * 4 + 3] = t4.w;
        }
    }
    if (tid < 64 || (tid >= 128 && tid < 192)) {
        const int c = tid & 63;   // lane within the solve wave
        // one pass over SM per wave: lane c holds e in [32c, 32c+32)
        float sm[32];
        {
            const int lb = 33 * c;
#pragma unroll
            for (int r8 = 0; r8 < 8; r8++) {
                const float4 t4 = *(const float4*)&SMf[lb + r8 * 4];
                sm[r8 * 4 + 0] = -t4.x; sm[r8 * 4 + 1] = -t4.y;
                sm[r8 * 4 + 2] = -t4.z; sm[r8 * 4 + 3] = -t4.w;
            }
        }
        // register forward substitution; SM broadcast via readlane (VALU only)
#pragma unroll
        for (int j = 0; j < 63; j++) {
#pragma unroll
            for (int i = j + 1; i < 64; i++) {
                const int e = (i * (i - 1)) / 2 + j;
                const float s = __int_as_float(__builtin_amdgcn_readlane(
                    __float_as_int(sm[e & 31]), e >> 5));
                sol[i] += s * sol[j];
            }
        }
        // stores straight from registers: row c of W^T/U^T ([dim][token])
        float* dst = (tid < 64 ? WTg : UTg) +
                     (size_t)(bh * NCC + n) * Cc * Dd + (size_t)c * 64;
#pragma unroll
        for (int j4 = 0; j4 < 16; j4++)
            *(float4*)(dst + j4 * 4) = make_float4(sol[j4 * 4 + 0], sol[j4 * 4 + 1],
                                                   sol[j4 * 4 + 2], sol[j4 * 4 + 3]);
        float* lst = (tid < 64 ? wlast : ulast);
        lst[(size_t)(bh * NCC + n) * 64 + c] = sol[63];
    }
}

// ---------------------------------------------------------------------------
// kB: chunk-level delta rule (16 blocks). Register solve.  (unchanged)
// ---------------------------------------------------------------------------
__global__ __launch_bounds__(256) void kB(
    const float* __restrict__ wlast, const float* __restrict__ ulast,
    float* __restrict__ Uvg)
{
    const int bh = blockIdx.x, tid = threadIdx.x;
    __shared__ float WL[64 * PD];
    __shared__ float UL[64 * PD];
    __shared__ float SM[64 * PD];
    const size_t gbase = (size_t)bh * NCC * 64;

#pragma unroll
    for (int p = 0; p < 4; p++) {
        const int flat = p * 1024 + tid * 4;
        const int m = flat >> 6, d = flat & 63;
        *(float4*)&WL[m * PD + d] = *(const float4*)(wlast + gbase + flat);
        *(float4*)&UL[m * PD + d] = *(const float4*)(ulast + gbase + flat);
    }
    __syncthreads();

    if (tid < 136) {
        int ti = (int)((sqrtf(8.0f * (float)tid + 1.0f) - 1.0f) * 0.5f);
        while (ti * (ti + 1) / 2 > tid) --ti;
        while ((ti + 1) * (ti + 2) / 2 <= tid) ++ti;
        const int tj = tid - ti * (ti + 1) / 2;
        const int i0 = ti * 4, j0 = tj * 4;
        float sa[4][4];
#pragma unroll
        for (int r = 0; r < 4; r++)
#pragma unroll
            for (int c2 = 0; c2 < 4; c2++) sa[r][c2] = 0.f;
        for (int d4 = 0; d4 < 16; d4++) {
            const int d = d4 * 4;
            float4 ar[4], bc[4];
#pragma unroll
            for (int r = 0; r < 4; r++) ar[r] = *(const float4*)&WL[(i0 + r) * PD + d];
#pragma unroll
            for (int c2 = 0; c2 < 4; c2++) bc[c2] = *(const float4*)&WL[(j0 + c2) * PD + d];
#pragma unroll
            for (int r = 0; r < 4; r++)
#pragma unroll
                for (int c2 = 0; c2 < 4; c2++)
                    sa[r][c2] += ar[r].x * bc[c2].x + ar[r].y * bc[c2].y +
                                 ar[r].z * bc[c2].z + ar[r].w * bc[c2].w;
        }
#pragma unroll
        for (int r = 0; r < 4; r++)
            *(float4*)&SM[(i0 + r) * PD + j0] =
                make_float4(sa[r][0], sa[r][1], sa[r][2], sa[r][3]);
    }
    __syncthreads();

    if (tid < 64) {
        const int e = tid;
        float sol[64];
#pragma unroll
        for (int m = 0; m < 64; m++) sol[m] = UL[m * PD + e];
#pragma unroll
        for (int b = 0; b < 8; b++) {
            const int i0 = b * 8;
            float acc[8];
#pragma unroll
            for (int r = 0; r < 8; r++) acc[r] = sol[i0 + r];
#pragma unroll
            for (int j4 = 0; j4 < 2 * b; j4++) {
                const int j = j4 * 4;
                const float s0 = sol[j + 0], s1 = sol[j + 1];
                const float s2 = sol[j + 2], s3 = sol[j + 3];
#pragma unroll
                for (int r = 0; r < 8; r++) {
                    const float4 m4 = *(const float4*)&SM[(i0 + r) * PD + j];
                    acc[r] -= m4.x * s0 + m4.y * s1 + m4.z * s2 + m4.w * s3;
                }
            }
#pragma unroll
            for (int il = 1; il < 8; il++)
#pragma unroll
                for (int jl = 0; jl < il; jl++)
                    acc[il] -= SM[(i0 + il) * PD + i0 + jl] * acc[jl];
#pragma unroll
            for (int r = 0; r < 8; r++) sol[i0 + r] = acc[r];
        }
#pragma unroll
        for (int m = 0; m < 64; m++) Uvg[gbase + (size_t)m * 64 + e] = sol[m];
    }
}

// ---------------------------------------------------------------------------
// kC: output. 512 blocks; block px handles the balanced chunk pair
// (63-px, px) so every block has identical total ph1 work (sum of n = 63).
//   h[d][e] = sum_{m<n} wlast[m][d]*Uval[m][e];  out = qn.*(U - W h) + qn h
// (round-0 exact -- the only shape that hasn't regressed)
// ---------------------------------------------------------------------------
__global__ __launch_bounds__(256, 3) void kC(
    const float* __restrict__ qg, const float* __restrict__ WTg,
    const float* __restrict__ UTg, const float* __restrict__ wlast,
    const float* __restrict__ Uvg, float* __restrict__ outg)
{
    const int px = blockIdx.x, bh = blockIdx.y, tid = threadIdx.x;
    __shared__ float X1[64 * 64];   // wlast[m][d] -> W^T[d][t]
    __shared__ float X2[64 * PD];   // Uval[m][e]  -> qn^T[d][t]  (padded)
    __shared__ float HB[64 * 64];   // h[d][e]
    const size_t lbase = (size_t)bh * NCC * 64;
    const int t0 = (tid >> 4) * 4, e0 = (tid & 15) * 4;

    for (int pass = 0; pass < 2; ++pass) {
        const int n = pass ? px : 63 - px;
        const size_t qbase = ((size_t)bh * SLEN + (size_t)n * Cc) * Dd;
        const size_t wbase = (size_t)(bh * NCC + n) * Cc * Dd;
        if (pass) __syncthreads();   // protect LDS reuse across passes

        float4 qa[4], wt[4];
        float qinv[4];
#pragma unroll
        for (int p = 0; p < 4; p++) {
            const int flat = p * 1024 + tid * 4;
            const int m = flat >> 6, d = flat & 63;
            *(float4*)&X1[m * 64 + d] = *(const float4*)(wlast + lbase + flat);
            *(float4*)&X2[m * PD + d] = *(const float4*)(Uvg + lbase + flat);
            qa[p] = *(const float4*)(qg + qbase + flat);
            float ss = qa[p].x * qa[p].x + qa[p].y * qa[p].y +
                       qa[p].z * qa[p].z + qa[p].w * qa[p].w;
            ss += __shfl_xor(ss, 1); ss += __shfl_xor(ss, 2);
            ss += __shfl_xor(ss, 4); ss += __shfl_xor(ss, 8);
            qinv[p] = 1.0f / (sqrtf(ss) + EPSF);
            wt[p] = *(const float4*)(WTg + wbase + flat);
        }
        __syncthreads();

        // ph1: h tile accumulation over earlier chunks
        float ha[4][4];
#pragma unroll
        for (int r = 0; r < 4; r++)
#pragma unroll
            for (int c2 = 0; c2 < 4; c2++) ha[r][c2] = 0.f;
        for (int m = 0; m < n; m++) {
            const float4 a = *(const float4*)&X1[m * 64 + t0];
            const float4 b = *(const float4*)&X2[m * PD + e0];
            const float av[4] = {a.x, a.y, a.z, a.w};
            const float bv[4] = {b.x, b.y, b.z, b.w};
#pragma unroll
            for (int r = 0; r < 4; r++)
#pragma unroll
                for (int c2 = 0; c2 < 4; c2++) ha[r][c2] += av[r] * bv[c2];
        }
#pragma unroll
        for (int r = 0; r < 4; r++)
            *(float4*)&HB[(t0 + r) * 64 + e0] =
                make_float4(ha[r][0], ha[r][1], ha[r][2], ha[r][3]);
        __syncthreads();

        // rebuild: X1 <- W^T (flat from regs), X2 <- qn^T (transposed writes)
#pragma unroll
        for (int p = 0; p < 4; p++) {
            const int flat = p * 1024 + tid * 4;
            const int d = flat >> 6, t = flat & 63;
            *(float4*)&X1[d * 64 + t] = wt[p];
            const int row = d, d0 = t;   // q decode: (token row, dim d0)
            X2[(d0 + 0) * PD + row] = qa[p].x * qinv[p];
            X2[(d0 + 1) * PD + row] = qa[p].y * qinv[p];
            X2[(d0 + 2) * PD + row] = qa[p].z * qinv[p];
            X2[(d0 + 3) * PD + row] = qa[p].w * qinv[p];
        }
        __syncthreads();

        // ph3: kth = W h, oin = qn h
        float kth[4][4], oin[4][4];
#pragma unroll
        for (int r = 0; r < 4; r++)
#pragma unroll
            for (int c2 = 0; c2 < 4; c2++) { kth[r][c2] = 0.f; oin[r][c2] = 0.f; }
#pragma unroll 4
        for (int d = 0; d < 64; d++) {
            const float4 wv = *(const float4*)&X1[d * 64 + t0];
            const float4 qv = *(const float4*)&X2[d * PD + t0];
            const float4 hv = *(const float4*)&HB[d * 64 + e0];
            const float wa[4] = {wv.x, wv.y, wv.z, wv.w};
            const float qa2[4] = {qv.x, qv.y, qv.z, qv.w};
            const float hv4[4] = {hv.x, hv.y, hv.z, hv.w};
#pragma unroll
            for (int r = 0; r < 4; r++)
#pragma unroll
                for (int c2 = 0; c2 < 4; c2++) {
                    kth[r][c2] += wa[r] * hv4[c2];
                    oin[r][c2] += qa2[r] * hv4[c2];
                }
        }

        // epilogue: U^T tile from global (L2-hot), qn from X2
        float* oc = outg + qbase;
        float o4[4][4];
#pragma unroll
        for (int s = 0; s < 4; s++) {
            const float4 u4 = *(const float4*)(UTg + wbase + (size_t)(e0 + s) * 64 + t0);
            const float4 q4 = *(const float4*)&X2[(e0 + s) * PD + t0];
            o4[0][s] = q4.x * (u4.x - kth[0][s]) + oin[0][s];
            o4[1][s] = q4.y * (u4.y - kth[1][s]) + oin[1][s];
            o4[2][s] = q4.z * (u4.z - kth[2][s]) + oin[2][s];
            o4[3][s] = q4.w * (u4.w - kth[3][s]) + oin[3][s];
        }
#pragma unroll
        for (int r = 0; r < 4; r++)
            *(float4*)(oc + (size_t)(t0 + r) * 64 + e0) =
                make_float4(o4[r][0], o4[r][1], o4[r][2], o4[r][3]);
    }
}

extern "C" void kernel_launch(void* const* d_in, const int* in_sizes, int n_in,
                              void* d_out, int out_size, void* d_ws, size_t ws_size,
                              hipStream_t stream) {
    const float* q    = (const float*)d_in[0];
    const float* k    = (const float*)d_in[1];
    const float* v    = (const float*)d_in[2];
    const float* beta = (const float*)d_in[3];
    float* out = (float*)d_out;

    float* WTg   = (float*)d_ws;                              // [BH][NC][64][64] (W^T)
    float* UTg   = WTg + (size_t)BHn * NCC * Cc * Dd;         // [BH][NC][64][64] (U^T)
    float* wlast = UTg + (size_t)BHn * NCC * Cc * Dd;         // [BH][NC][64]
    float* ulast = wlast + (size_t)BHn * NCC * 64;            // [BH][NC][64]
    float* Uvg   = ulast + (size_t)BHn * NCC * 64;            // [BH][NC][64]

    kA<<<dim3(NCC, BHn), 256, 0, stream>>>(k, v, beta, WTg, UTg, wlast, ulast);
    kB<<<dim3(BHn), 256, 0, stream>>>(wlast, ulast, Uvg);
    kC<<<dim3(32, BHn), 256, 0, stream>>>(q, WTg, UTg, wlast, Uvg, out);
}

// Round 7
// 84.296 us; speedup vs baseline: 1.0752x; 1.0261x over previous
//
#include <hip/hip_runtime.h>
#include <math.h>

#define BHn 16
#define SLEN 4096
#define Dd 64
#define Cc 64
#define NCC 64
#define EPSF 1e-6f
#define PD 65

// ---------------------------------------------------------------------------
// kA: per (head, chunk) UT transform.  (round-0 exact — best measured)
//   KT[d][t] = l2norm(k)^T (pad-65 => conflict-free transposed writes)
//   SM[i][j] = g_i * (kn_i . kn_j)   (lower tiles only)
//   Wave0 solves W columns in registers; wave1 solves U columns in registers.
//   Stores W^T,U^T ([dim][token]) + last rows, straight from registers.
// ---------------------------------------------------------------------------
__global__ __launch_bounds__(256, 4) void kA(
    const float* __restrict__ kg, const float* __restrict__ vg,
    const float* __restrict__ betag, float* __restrict__ WTg, float* __restrict__ UTg,
    float* __restrict__ wlast, float* __restrict__ ulast)
{
    const int n = blockIdx.x, bh = blockIdx.y, tid = threadIdx.x;
    __shared__ float KT[64 * PD];   // kn^T, then (g*v)^T
    __shared__ float SM[64 * PD];
    __shared__ float gl[64];

    const size_t base = ((size_t)bh * SLEN + (size_t)n * Cc) * Dd;

    if (tid < 64) {
        const float b = betag[(size_t)bh * SLEN + n * Cc + tid];
        gl[tid] = fminf(fmaxf(b, EPSF), 1.0f - EPSF);
    }
    // build KT = kn^T : coalesced float4 row loads, 16-lane norm, transposed scalar
    // writes (bank = (d+t)%32, exactly 2 lanes/bank => free)
#pragma unroll
    for (int p = 0; p < 4; p++) {
        const int flat = p * 1024 + tid * 4;
        const int row = flat >> 6, d0 = flat & 63;
        const float4 a = *(const float4*)(kg + base + flat);
        float ss = a.x * a.x + a.y * a.y + a.z * a.z + a.w * a.w;
        ss += __shfl_xor(ss, 1); ss += __shfl_xor(ss, 2);
        ss += __shfl_xor(ss, 4); ss += __shfl_xor(ss, 8);
        const float inv = 1.0f / (sqrtf(ss) + EPSF);
        KT[(d0 + 0) * PD + row] = a.x * inv;
        KT[(d0 + 1) * PD + row] = a.y * inv;
        KT[(d0 + 2) * PD + row] = a.z * inv;
        KT[(d0 + 3) * PD + row] = a.w * inv;
    }
    __syncthreads();

    float sol[64];
    if (tid < 64) {
        // wave0: load W solve column = KT[tid][:] * g[:]  (runs concurrent with S)
#pragma unroll
        for (int j4 = 0; j4 < 16; j4++) {
            const float4 t4 = *(const float4*)&KT[tid * PD + j4 * 4];
            sol[j4 * 4 + 0] = t4.x * gl[j4 * 4 + 0];
            sol[j4 * 4 + 1] = t4.y * gl[j4 * 4 + 1];
            sol[j4 * 4 + 2] = t4.z * gl[j4 * 4 + 2];
            sol[j4 * 4 + 3] = t4.w * gl[j4 * 4 + 3];
        }
    } else if (tid < 200) {
        // threads 64..199: S lower 4x4 tiles from KT; rows scaled by g_i
        const int t = tid - 64;
        int ti = (int)((sqrtf(8.0f * (float)t + 1.0f) - 1.0f) * 0.5f);
        while (ti * (ti + 1) / 2 > t) --ti;
        while ((ti + 1) * (ti + 2) / 2 <= t) ++ti;
        const int tj = t - ti * (ti + 1) / 2;
        const int i0 = ti * 4, j0 = tj * 4;
        float sa[4][4];
#pragma unroll
        for (int r = 0; r < 4; r++)
#pragma unroll
            for (int c2 = 0; c2 < 4; c2++) sa[r][c2] = 0.f;
        for (int d = 0; d < 64; d++) {
            const float4 a = *(const float4*)&KT[d * PD + i0];
            const float4 b = *(const float4*)&KT[d * PD + j0];
            const float av[4] = {a.x, a.y, a.z, a.w};
            const float bv[4] = {b.x, b.y, b.z, b.w};
#pragma unroll
            for (int r = 0; r < 4; r++)
#pragma unroll
                for (int c2 = 0; c2 < 4; c2++) sa[r][c2] += av[r] * bv[c2];
        }
#pragma unroll
        for (int r = 0; r < 4; r++) {
            const float gg = gl[i0 + r];
            *(float4*)&SM[(i0 + r) * PD + j0] =
                make_float4(sa[r][0] * gg, sa[r][1] * gg, sa[r][2] * gg, sa[r][3] * gg);
        }
    }
    __syncthreads();

    // overwrite KT with (g*v)^T
#pragma unroll
    for (int p = 0; p < 4; p++) {
        const int flat = p * 1024 + tid * 4;
        const int row = flat >> 6, d0 = flat & 63;
        const float4 a = *(const float4*)(vg + base + flat);
        const float gg = gl[row];
        KT[(d0 + 0) * PD + row] = a.x * gg;
        KT[(d0 + 1) * PD + row] = a.y * gg;
        KT[(d0 + 2) * PD + row] = a.z * gg;
        KT[(d0 + 3) * PD + row] = a.w * gg;
    }
    __syncthreads();

    if (tid >= 64 && tid < 128) {
        // wave1: load U solve column = (g*v)^T row
        const int c = tid - 64;
#pragma unroll
        for (int j4 = 0; j4 < 16; j4++) {
            const float4 t4 = *(const float4*)&KT[c * PD + j4 * 4];
            sol[j4 * 4 + 0] = t4.x; sol[j4 * 4 + 1] = t4.y;
            sol[j4 * 4 + 2] = t4.z; sol[j4 * 4 + 3] = t4.w;
        }
    }
    if (tid < 128) {
        const int c = tid & 63;
        // register forward substitution; SM reads are wave-uniform broadcasts
#pragma unroll
        for (int b = 0; b < 8; b++) {
            const int i0 = b * 8;
            float acc[8];
#pragma unroll
            for (int r = 0; r < 8; r++) acc[r] = sol[i0 + r];
#pragma unroll
            for (int j4 = 0; j4 < 2 * b; j4++) {
                const int j = j4 * 4;
                const float s0 = sol[j + 0], s1 = sol[j + 1];
                const float s2 = sol[j + 2], s3 = sol[j + 3];
#pragma unroll
                for (int r = 0; r < 8; r++) {
                    const float4 m4 = *(const float4*)&SM[(i0 + r) * PD + j];
                    acc[r] -= m4.x * s0 + m4.y * s1 + m4.z * s2 + m4.w * s3;
                }
            }
#pragma unroll
            for (int il = 1; il < 8; il++)
#pragma unroll
                for (int jl = 0; jl < il; jl++)
                    acc[il] -= SM[(i0 + il) * PD + i0 + jl] * acc[jl];
#pragma unroll
            for (int r = 0; r < 8; r++) sol[i0 + r] = acc[r];
        }
        // stores straight from registers: row c of W^T/U^T ([dim][token])
        float* dst = (tid < 64 ? WTg : UTg) +
                     (size_t)(bh * NCC + n) * Cc * Dd + (size_t)c * 64;
#pragma unroll
        for (int j4 = 0; j4 < 16; j4++)
            *(float4*)(dst + j4 * 4) = make_float4(sol[j4 * 4 + 0], sol[j4 * 4 + 1],
                                                   sol[j4 * 4 + 2], sol[j4 * 4 + 3]);
        float* lst = (tid < 64 ? wlast : ulast);
        lst[(size_t)(bh * NCC + n) * 64 + c] = sol[63];
    }
}

// ---------------------------------------------------------------------------
// kB: chunk-level delta rule (16 blocks). Register solve.  (unchanged)
// ---------------------------------------------------------------------------
__global__ __launch_bounds__(256) void kB(
    const float* __restrict__ wlast, const float* __restrict__ ulast,
    float* __restrict__ Uvg)
{
    const int bh = blockIdx.x, tid = threadIdx.x;
    __shared__ float WL[64 * PD];
    __shared__ float UL[64 * PD];
    __shared__ float SM[64 * PD];
    const size_t gbase = (size_t)bh * NCC * 64;

#pragma unroll
    for (int p = 0; p < 4; p++) {
        const int flat = p * 1024 + tid * 4;
        const int m = flat >> 6, d = flat & 63;
        *(float4*)&WL[m * PD + d] = *(const float4*)(wlast + gbase + flat);
        *(float4*)&UL[m * PD + d] = *(const float4*)(ulast + gbase + flat);
    }
    __syncthreads();

    if (tid < 136) {
        int ti = (int)((sqrtf(8.0f * (float)tid + 1.0f) - 1.0f) * 0.5f);
        while (ti * (ti + 1) / 2 > tid) --ti;
        while ((ti + 1) * (ti + 2) / 2 <= tid) ++ti;
        const int tj = tid - ti * (ti + 1) / 2;
        const int i0 = ti * 4, j0 = tj * 4;
        float sa[4][4];
#pragma unroll
        for (int r = 0; r < 4; r++)
#pragma unroll
            for (int c2 = 0; c2 < 4; c2++) sa[r][c2] = 0.f;
        for (int d4 = 0; d4 < 16; d4++) {
            const int d = d4 * 4;
            float4 ar[4], bc[4];
#pragma unroll
            for (int r = 0; r < 4; r++) ar[r] = *(const float4*)&WL[(i0 + r) * PD + d];
#pragma unroll
            for (int c2 = 0; c2 < 4; c2++) bc[c2] = *(const float4*)&WL[(j0 + c2) * PD + d];
#pragma unroll
            for (int r = 0; r < 4; r++)
#pragma unroll
                for (int c2 = 0; c2 < 4; c2++)
                    sa[r][c2] += ar[r].x * bc[c2].x + ar[r].y * bc[c2].y +
                                 ar[r].z * bc[c2].z + ar[r].w * bc[c2].w;
        }
#pragma unroll
        for (int r = 0; r < 4; r++)
            *(float4*)&SM[(i0 + r) * PD + j0] =
                make_float4(sa[r][0], sa[r][1], sa[r][2], sa[r][3]);
    }
    __syncthreads();

    if (tid < 64) {
        const int e = tid;
        float sol[64];
#pragma unroll
        for (int m = 0; m < 64; m++) sol[m] = UL[m * PD + e];
#pragma unroll
        for (int b = 0; b < 8; b++) {
            const int i0 = b * 8;
            float acc[8];
#pragma unroll
            for (int r = 0; r < 8; r++) acc[r] = sol[i0 + r];
#pragma unroll
            for (int j4 = 0; j4 < 2 * b; j4++) {
                const int j = j4 * 4;
                const float s0 = sol[j + 0], s1 = sol[j + 1];
                const float s2 = sol[j + 2], s3 = sol[j + 3];
#pragma unroll
                for (int r = 0; r < 8; r++) {
                    const float4 m4 = *(const float4*)&SM[(i0 + r) * PD + j];
                    acc[r] -= m4.x * s0 + m4.y * s1 + m4.z * s2 + m4.w * s3;
                }
            }
#pragma unroll
            for (int il = 1; il < 8; il++)
#pragma unroll
                for (int jl = 0; jl < il; jl++)
                    acc[il] -= SM[(i0 + il) * PD + i0 + jl] * acc[jl];
#pragma unroll
            for (int r = 0; r < 8; r++) sol[i0 + r] = acc[r];
        }
#pragma unroll
        for (int m = 0; m < 64; m++) Uvg[gbase + (size_t)m * 64 + e] = sol[m];
    }
}

// ---------------------------------------------------------------------------
// kC round-7: single-chunk blocks for residency.  1024 blocks (was 512
// chunk-pair blocks at 2 passes).  Round-0's 512 blocks = 2/CU resident
// (grid-limited; LDS 49.6K permits 3/CU) = 8 waves/CU, occupancy 14%.
// Now 1024 blocks -> 768 concurrently resident (3/CU), +50% waves.
// Per-block math/staging identical to one round-0 pass (each pass already
// re-staged everything, so total instruction counts are unchanged).
// Heavy chunks first (n = 63-bx) so greedy scheduling absorbs the ph1
// imbalance (ph1 cost ~ n): light blocks retire early and backfill.
// ---------------------------------------------------------------------------
__global__ __launch_bounds__(256, 3) void kC(
    const float* __restrict__ qg, const float* __restrict__ WTg,
    const float* __restrict__ UTg, const float* __restrict__ wlast,
    const float* __restrict__ Uvg, float* __restrict__ outg)
{
    const int bx = blockIdx.x, bh = blockIdx.y, tid = threadIdx.x;
    __shared__ float X1[64 * 64];   // wlast[m][d] -> W^T[d][t]   (never transposed-written)
    __shared__ float X2[64 * PD];   // Uval[m][e]  -> qn^T[d][t]  (padded: transposed writes)
    __shared__ float HB[64 * 64];   // h[d][e]
    const size_t lbase = (size_t)bh * NCC * 64;
    const int t0 = (tid >> 4) * 4, e0 = (tid & 15) * 4;

    const int n = 63 - bx;   // heavy chunks dispatched first
    const size_t qbase = ((size_t)bh * SLEN + (size_t)n * Cc) * Dd;
    const size_t wbase = (size_t)(bh * NCC + n) * Cc * Dd;

    float4 qa[4], wt[4];
    float qinv[4];
#pragma unroll
    for (int p = 0; p < 4; p++) {
        const int flat = p * 1024 + tid * 4;
        const int m = flat >> 6, d = flat & 63;
        *(float4*)&X1[m * 64 + d] = *(const float4*)(wlast + lbase + flat);
        *(float4*)&X2[m * PD + d] = *(const float4*)(Uvg + lbase + flat);
        qa[p] = *(const float4*)(qg + qbase + flat);
        float ss = qa[p].x * qa[p].x + qa[p].y * qa[p].y +
                   qa[p].z * qa[p].z + qa[p].w * qa[p].w;
        ss += __shfl_xor(ss, 1); ss += __shfl_xor(ss, 2);
        ss += __shfl_xor(ss, 4); ss += __shfl_xor(ss, 8);
        qinv[p] = 1.0f / (sqrtf(ss) + EPSF);
        wt[p] = *(const float4*)(WTg + wbase + flat);
    }
    __syncthreads();

    // ph1: h tile accumulation over earlier chunks
    float ha[4][4];
#pragma unroll
    for (int r = 0; r < 4; r++)
#pragma unroll
        for (int c2 = 0; c2 < 4; c2++) ha[r][c2] = 0.f;
    for (int m = 0; m < n; m++) {
        const float4 a = *(const float4*)&X1[m * 64 + t0];
        const float4 b = *(const float4*)&X2[m * PD + e0];
        const float av[4] = {a.x, a.y, a.z, a.w};
        const float bv[4] = {b.x, b.y, b.z, b.w};
#pragma unroll
        for (int r = 0; r < 4; r++)
#pragma unroll
            for (int c2 = 0; c2 < 4; c2++) ha[r][c2] += av[r] * bv[c2];
    }
#pragma unroll
    for (int r = 0; r < 4; r++)
        *(float4*)&HB[(t0 + r) * 64 + e0] =
            make_float4(ha[r][0], ha[r][1], ha[r][2], ha[r][3]);
    __syncthreads();

    // rebuild: X1 <- W^T (flat from regs), X2 <- qn^T (transposed writes)
#pragma unroll
    for (int p = 0; p < 4; p++) {
        const int flat = p * 1024 + tid * 4;
        const int d = flat >> 6, t = flat & 63;
        *(float4*)&X1[d * 64 + t] = wt[p];
        const int row = d, d0 = t;   // q decode: (token row, dim d0)
        X2[(d0 + 0) * PD + row] = qa[p].x * qinv[p];
        X2[(d0 + 1) * PD + row] = qa[p].y * qinv[p];
        X2[(d0 + 2) * PD + row] = qa[p].z * qinv[p];
        X2[(d0 + 3) * PD + row] = qa[p].w * qinv[p];
    }
    __syncthreads();

    // ph3: kth = W h, oin = qn h
    float kth[4][4], oin[4][4];
#pragma unroll
    for (int r = 0; r < 4; r++)
#pragma unroll
        for (int c2 = 0; c2 < 4; c2++) { kth[r][c2] = 0.f; oin[r][c2] = 0.f; }
#pragma unroll 4
    for (int d = 0; d < 64; d++) {
        const float4 wv = *(const float4*)&X1[d * 64 + t0];
        const float4 qv = *(const float4*)&X2[d * PD + t0];
        const float4 hv = *(const float4*)&HB[d * 64 + e0];
        const float wa[4] = {wv.x, wv.y, wv.z, wv.w};
        const float qa2[4] = {qv.x, qv.y, qv.z, qv.w};
        const float hv4[4] = {hv.x, hv.y, hv.z, hv.w};
#pragma unroll
        for (int r = 0; r < 4; r++)
#pragma unroll
            for (int c2 = 0; c2 < 4; c2++) {
                kth[r][c2] += wa[r] * hv4[c2];
                oin[r][c2] += qa2[r] * hv4[c2];
            }
    }

    // epilogue: U^T tile from global (L2-hot), qn from X2
    float* oc = outg + qbase;
    float o4[4][4];
#pragma unroll
    for (int s = 0; s < 4; s++) {
        const float4 u4 = *(const float4*)(UTg + wbase + (size_t)(e0 + s) * 64 + t0);
        const float4 q4 = *(const float4*)&X2[(e0 + s) * PD + t0];
        o4[0][s] = q4.x * (u4.x - kth[0][s]) + oin[0][s];
        o4[1][s] = q4.y * (u4.y - kth[1][s]) + oin[1][s];
        o4[2][s] = q4.z * (u4.z - kth[2][s]) + oin[2][s];
        o4[3][s] = q4.w * (u4.w - kth[3][s]) + oin[3][s];
    }
#pragma unroll
    for (int r = 0; r < 4; r++)
        *(float4*)(oc + (size_t)(t0 + r) * 64 + e0) =
            make_float4(o4[r][0], o4[r][1], o4[r][2], o4[r][3]);
}

extern "C" void kernel_launch(void* const* d_in, const int* in_sizes, int n_in,
                              void* d_out, int out_size, void* d_ws, size_t ws_size,
                              hipStream_t stream) {
    const float* q    = (const float*)d_in[0];
    const float* k    = (const float*)d_in[1];
    const float* v    = (const float*)d_in[2];
    const float* beta = (const float*)d_in[3];
    float* out = (float*)d_out;

    float* WTg   = (float*)d_ws;                              // [BH][NC][64][64] (W^T)
    float* UTg   = WTg + (size_t)BHn * NCC * Cc * Dd;         // [BH][NC][64][64] (U^T)
    float* wlast = UTg + (size_t)BHn * NCC * Cc * Dd;         // [BH][NC][64]
    float* ulast = wlast + (size_t)BHn * NCC * 64;            // [BH][NC][64]
    float* Uvg   = ulast + (size_t)BHn * NCC * 64;            // [BH][NC][64]

    kA<<<dim3(NCC, BHn), 256, 0, stream>>>(k, v, beta, WTg, UTg, wlast, ulast);
    kB<<<dim3(BHn), 256, 0, stream>>>(wlast, ulast, Uvg);
    kC<<<dim3(64, BHn), 256, 0, stream>>>(q, WTg, UTg, wlast, Uvg, out);
}